// Round 1
// baseline (26702.045 us; speedup 1.0000x reference)
//
#include <hip/hip_runtime.h>

// DeepLSTM persistent wavefront pipeline for MI355X (gfx950).
// 256 WGs (1/CU): layer = blockIdx/64, slice of 8 hidden units = blockIdx%64.
// Weights resident in LDS as hi/lo bf16 split; h passed between WGs as bf16
// via a full-history buffer in d_ws with per-(layer,t) flag counters.

constexpr int Bv = 32;
constexpr int Tv = 512;
constexpr int Iv = 256;
constexpr int Hv = 512;
constexpr int LAYv = 4;
constexpr int SLICES = 64;   // WGs per layer
constexpr int THREADS = 256; // 4 waves
constexpr int NKK = 32;      // max K/32 (512 recurrent + 512 input)
constexpr int WTAB = 2 * NKK * 64 * 8;            // shorts per weight table (32768)
constexpr unsigned SMEM_BYTES = WTAB * 2 * 2 + 32 * 33 * 4; // 135296

typedef short sfrag __attribute__((ext_vector_type(8)));
typedef float facc  __attribute__((ext_vector_type(4)));
typedef float f32x4 __attribute__((ext_vector_type(4)));

struct Params {
  const float *x;
  const float *Wx0i, *Wx0f, *Wx0o, *Wx0c;
  const float *Wxi, *Wxf, *Wxo, *Wxc;
  const float *Whi, *Whf, *Who, *Whc;
  const float *bi, *bf, *bo, *bc;
  float *out;
  unsigned short *hbuf; // [(T+1)][L][B][H] bf16 slots
  int *flags;           // [(T+1)][L]
};

__device__ __forceinline__ unsigned short f2bf(float f) {
  unsigned int u = __builtin_bit_cast(unsigned int, f);
  u += 0x7FFFu + ((u >> 16) & 1u); // RNE
  return (unsigned short)(u >> 16);
}
__device__ __forceinline__ float bf2f(unsigned short s) {
  unsigned int u = ((unsigned int)s) << 16;
  return __builtin_bit_cast(float, u);
}

__global__ void __launch_bounds__(THREADS, 1) lstm_pipeline(Params p) {
  const int wg = blockIdx.x;
  const int l = wg >> 6;       // layer 0..3
  const int slice = wg & 63;   // 8-unit slice
  const int tid = threadIdx.x;
  const int lane = tid & 63;
  const int w = tid >> 6;      // wave 0..3
  const int mt = w & 1;        // M-tile (batch 16-block)
  const int nt = w >> 1;       // N-tile (gate-col 16-block)

  extern __shared__ char smem[];
  unsigned short *wlds_hi = (unsigned short *)smem;          // [2][32][64][8]
  unsigned short *wlds_lo = wlds_hi + WTAB;
  float *preact = (float *)(smem + (size_t)WTAB * 2 * 2);    // [32][33]

  // gate-indexed weight bases for this layer
  const float *Wh[4] = {p.Whi + (size_t)l * Hv * Hv, p.Whf + (size_t)l * Hv * Hv,
                        p.Who + (size_t)l * Hv * Hv, p.Whc + (size_t)l * Hv * Hv};
  const float *Wx[4];
  if (l == 0) { Wx[0] = p.Wx0i; Wx[1] = p.Wx0f; Wx[2] = p.Wx0o; Wx[3] = p.Wx0c; }
  else {
    size_t o = (size_t)(l - 1) * Hv * Hv;
    Wx[0] = p.Wxi + o; Wx[1] = p.Wxf + o; Wx[2] = p.Wxo + o; Wx[3] = p.Wxc + o;
  }
  const int kx_max = (l == 0) ? Iv : Hv;

  // ---- stage weight slice into LDS in MFMA B-fragment order (hi/lo split) ----
  for (int idx = tid; idx < 2 * NKK * 64; idx += THREADS) {
    int lanei = idx & 63;
    int kk = (idx >> 6) & (NKK - 1);
    int nti = idx >> 11;
    int kbase = kk * 32 + (lanei >> 4) * 8;
    int n = nti * 16 + (lanei & 15); // gate-col within 32: n = jj*4 + g
    int jj = n >> 2, g = n & 3;
    int col = slice * 8 + jj;
    sfrag vh, vl;
#pragma unroll
    for (int j = 0; j < 8; ++j) {
      int k = kbase + j;
      float wv;
      if (k < Hv) wv = Wh[g][(size_t)k * Hv + col];
      else {
        int kx = k - Hv;
        wv = (kx < kx_max) ? Wx[g][(size_t)kx * Hv + col] : 0.f;
      }
      unsigned short h16 = f2bf(wv);
      vh[j] = (short)h16;
      vl[j] = (short)f2bf(wv - bf2f(h16));
    }
    *(sfrag *)&wlds_hi[(size_t)idx * 8] = vh;
    *(sfrag *)&wlds_lo[(size_t)idx * 8] = vl;
  }

  // epilogue thread mapping: bm = batch, um = unit-in-slice
  const int bm = tid >> 3;
  const int um = tid & 7;
  const int jg = slice * 8 + um;
  const float bia_i = p.bi[l * Hv + jg];
  const float bia_f = p.bf[l * Hv + jg];
  const float bia_o = p.bo[l * Hv + jg];
  const float bia_c = p.bc[l * Hv + jg];
  float cstate = 0.f;

  __syncthreads();

  const int m = mt * 16 + (lane & 15); // batch row for A fragment
  const int kgrp = lane >> 4;          // k-group 0..3
  int *flags = p.flags;
  unsigned short *hbuf = p.hbuf;

  for (int t = 0; t < Tv; ++t) {
    // ---- wait for dependencies ----
    if (tid == 0) {
      if (t > 0) {
        int fi = t * LAYv + l; // recurrent h[l][t-1]
        while (__hip_atomic_load(&flags[fi], __ATOMIC_RELAXED, __HIP_MEMORY_SCOPE_AGENT) < SLICES)
          __builtin_amdgcn_s_sleep(1);
      }
      if (l > 0) {
        int fi = (t + 1) * LAYv + (l - 1); // input h[l-1][t]
        while (__hip_atomic_load(&flags[fi], __ATOMIC_RELAXED, __HIP_MEMORY_SCOPE_AGENT) < SLICES)
          __builtin_amdgcn_s_sleep(1);
      }
    }
    __syncthreads();
    __threadfence(); // acquire: invalidate so cross-XCD h is re-fetched

    // ---- GEMM [32 x K] * [K x 32] into two independent acc chains ----
    facc acc0 = {0.f, 0.f, 0.f, 0.f};
    facc acc1 = {0.f, 0.f, 0.f, 0.f};
    const unsigned short *hrec =
        hbuf + ((size_t)(t * LAYv + l) * Bv * Hv) + (size_t)m * Hv;
#pragma unroll
    for (int kk = 0; kk < 16; ++kk) { // recurrent half
      int k = kk * 32 + kgrp * 8;
      sfrag a = *(const sfrag *)(hrec + k);
      sfrag bh = *(const sfrag *)&wlds_hi[(size_t)((nt * NKK + kk) * 64 + lane) * 8];
      sfrag bl = *(const sfrag *)&wlds_lo[(size_t)((nt * NKK + kk) * 64 + lane) * 8];
      acc0 = __builtin_amdgcn_mfma_f32_16x16x32_bf16(a, bh, acc0, 0, 0, 0);
      acc1 = __builtin_amdgcn_mfma_f32_16x16x32_bf16(a, bl, acc1, 0, 0, 0);
    }
    if (l == 0) {
#pragma unroll
      for (int kk = 0; kk < 8; ++kk) { // x input half (I=256)
        int kx = kk * 32 + kgrp * 8;
        const float *xp = p.x + ((size_t)m * Tv + t) * Iv + kx;
        f32x4 lo = *(const f32x4 *)xp;
        f32x4 hi = *(const f32x4 *)(xp + 4);
        sfrag a;
#pragma unroll
        for (int j = 0; j < 4; ++j) {
          a[j] = (short)f2bf(lo[j]);
          a[4 + j] = (short)f2bf(hi[j]);
        }
        sfrag bh = *(const sfrag *)&wlds_hi[(size_t)((nt * NKK + 16 + kk) * 64 + lane) * 8];
        sfrag bl = *(const sfrag *)&wlds_lo[(size_t)((nt * NKK + 16 + kk) * 64 + lane) * 8];
        acc0 = __builtin_amdgcn_mfma_f32_16x16x32_bf16(a, bh, acc0, 0, 0, 0);
        acc1 = __builtin_amdgcn_mfma_f32_16x16x32_bf16(a, bl, acc1, 0, 0, 0);
      }
    } else {
      const unsigned short *hin =
          hbuf + ((size_t)((t + 1) * LAYv + (l - 1)) * Bv * Hv) + (size_t)m * Hv;
#pragma unroll
      for (int kk = 0; kk < 16; ++kk) { // input half from layer below
        int k = kk * 32 + kgrp * 8;
        sfrag a = *(const sfrag *)(hin + k);
        sfrag bh = *(const sfrag *)&wlds_hi[(size_t)((nt * NKK + 16 + kk) * 64 + lane) * 8];
        sfrag bl = *(const sfrag *)&wlds_lo[(size_t)((nt * NKK + 16 + kk) * 64 + lane) * 8];
        acc0 = __builtin_amdgcn_mfma_f32_16x16x32_bf16(a, bh, acc0, 0, 0, 0);
        acc1 = __builtin_amdgcn_mfma_f32_16x16x32_bf16(a, bl, acc1, 0, 0, 0);
      }
    }

    // ---- scatter pre-activations to LDS ----
    {
      int row = mt * 16 + kgrp * 4;
      int coln = nt * 16 + (lane & 15);
#pragma unroll
      for (int r = 0; r < 4; ++r)
        preact[(row + r) * 33 + coln] = acc0[r] + acc1[r];
    }
    __syncthreads();

    // ---- gates / state update: one thread per (batch, unit) ----
    float pi = preact[bm * 33 + um * 4 + 0] + bia_i;
    float pf = preact[bm * 33 + um * 4 + 1] + bia_f;
    float po = preact[bm * 33 + um * 4 + 2] + bia_o;
    float pc = preact[bm * 33 + um * 4 + 3] + bia_c;
    float gi = 1.f / (1.f + __expf(-pi));
    float gf = 1.f / (1.f + __expf(-pf));
    float go = 1.f / (1.f + __expf(-po));
    float gc = tanhf(pc);
    cstate = gf * cstate + gi * gc;
    float hval = go * tanhf(cstate);

    hbuf[(size_t)((t + 1) * LAYv + l) * Bv * Hv + (size_t)bm * Hv + jg] = f2bf(hval);
    if (l == LAYv - 1)
      p.out[((size_t)bm * Tv + t) * Hv + jg] = hval;

    __syncthreads();  // drain all waves' stores (vmcnt 0 before barrier)
    __threadfence();  // release: write back L2 so other XCDs see h
    if (tid == 0)
      atomicAdd(&flags[(t + 1) * LAYv + l], 1);
  }
}

extern "C" void kernel_launch(void *const *d_in, const int *in_sizes, int n_in,
                              void *d_out, int out_size, void *d_ws, size_t ws_size,
                              hipStream_t stream) {
  Params prm;
  prm.x = (const float *)d_in[0];
  prm.Wx0i = (const float *)d_in[1];
  prm.Wx0f = (const float *)d_in[2];
  prm.Wx0o = (const float *)d_in[3];
  prm.Wx0c = (const float *)d_in[4];
  prm.Wxi = (const float *)d_in[5];
  prm.Wxf = (const float *)d_in[6];
  prm.Wxo = (const float *)d_in[7];
  prm.Wxc = (const float *)d_in[8];
  prm.Whi = (const float *)d_in[9];
  prm.Whf = (const float *)d_in[10];
  prm.Who = (const float *)d_in[11];
  prm.Whc = (const float *)d_in[12];
  prm.bi = (const float *)d_in[13];
  prm.bf = (const float *)d_in[14];
  prm.bo = (const float *)d_in[15];
  prm.bc = (const float *)d_in[16];
  prm.out = (float *)d_out;

  size_t hbytes = (size_t)(Tv + 1) * LAYv * Bv * Hv * sizeof(unsigned short);
  size_t fbytes = (size_t)(Tv + 1) * LAYv * sizeof(int);
  if (ws_size < hbytes + fbytes) return; // would need ~64.2 MB scratch
  prm.hbuf = (unsigned short *)d_ws;
  prm.flags = (int *)((char *)d_ws + hbytes);

  // reset flags and the t=0 zero h-slot every call (deterministic replays)
  hipMemsetAsync(prm.flags, 0, fbytes, stream);
  hipMemsetAsync(d_ws, 0, (size_t)LAYv * Bv * Hv * sizeof(unsigned short), stream);

  hipFuncSetAttribute(reinterpret_cast<const void *>(lstm_pipeline),
                      hipFuncAttributeMaxDynamicSharedMemorySize, (int)SMEM_BYTES);

  void *args[] = {(void *)&prm};
  hipLaunchCooperativeKernel(reinterpret_cast<void *>(lstm_pipeline),
                             dim3(LAYv * SLICES), dim3(THREADS), args,
                             SMEM_BYTES, stream);
}

// Round 2
// 5881.290 us; speedup vs baseline: 4.5402x; 4.5402x over previous
//
#include <hip/hip_runtime.h>

// DeepLSTM persistent wavefront pipeline for MI355X (gfx950).
// 256 WGs (1/CU): layer = blockIdx/64, slice of 8 hidden units = blockIdx%64.
// Weights resident in LDS as hi/lo bf16 split. Cross-WG h exchange via
// agent-scope relaxed atomics (sc0/sc1 cache-bypass) -- NO threadfence,
// no L2 writeback/invalidate. Per-slice flags avoid RMW contention.

constexpr int Bv = 32;
constexpr int Tv = 512;
constexpr int Iv = 256;
constexpr int Hv = 512;
constexpr int LAYv = 4;
constexpr int SLICES = 64;   // WGs per layer
constexpr int THREADS = 256; // 4 waves
constexpr int NKK = 32;      // max K/32 (512 recurrent + 512 input)
constexpr int WTAB = 2 * NKK * 64 * 8;            // shorts per weight table (32768)
constexpr unsigned SMEM_BYTES = WTAB * 2 * 2 + 32 * 33 * 4; // 135296

typedef short sfrag __attribute__((ext_vector_type(8)));
typedef float facc  __attribute__((ext_vector_type(4)));
typedef float f32x4 __attribute__((ext_vector_type(4)));

struct Params {
  const float *x;
  const float *Wx0i, *Wx0f, *Wx0o, *Wx0c;
  const float *Wxi, *Wxf, *Wxo, *Wxc;
  const float *Whi, *Whf, *Who, *Whc;
  const float *bi, *bf, *bo, *bc;
  float *out;
  unsigned short *hbuf; // [(T+1)][L][B][H] bf16 slots
  int *flags;           // per_slice: [(T+1)][L][SLICES] else [(T+1)][L]
  int per_slice;
};

__device__ __forceinline__ unsigned short f2bf(float f) {
  unsigned int u = __builtin_bit_cast(unsigned int, f);
  u += 0x7FFFu + ((u >> 16) & 1u); // RNE
  return (unsigned short)(u >> 16);
}
__device__ __forceinline__ float bf2f(unsigned short s) {
  unsigned int u = ((unsigned int)s) << 16;
  return __builtin_bit_cast(float, u);
}

// 16B load that bypasses L1/L2 (agent-coherent; sees other XCDs' h writes)
__device__ __forceinline__ sfrag ld16_agent(const unsigned short *ptr) {
  const unsigned long long *q = (const unsigned long long *)ptr;
  union { unsigned long long u[2]; sfrag s; } r;
  r.u[0] = __hip_atomic_load(q, __ATOMIC_RELAXED, __HIP_MEMORY_SCOPE_AGENT);
  r.u[1] = __hip_atomic_load(q + 1, __ATOMIC_RELAXED, __HIP_MEMORY_SCOPE_AGENT);
  return r.s;
}

__global__ void __launch_bounds__(THREADS, 1) lstm_pipeline(Params p) {
  const int wg = blockIdx.x;
  const int l = wg >> 6;       // layer 0..3
  const int slice = wg & 63;   // 8-unit slice
  const int tid = threadIdx.x;
  const int lane = tid & 63;
  const int w = tid >> 6;      // wave 0..3
  const int mt = w & 1;        // M-tile (batch 16-block)
  const int nt = w >> 1;       // N-tile (gate-col 16-block)

  extern __shared__ char smem[];
  unsigned short *wlds_hi = (unsigned short *)smem;          // [2][32][64][8]
  unsigned short *wlds_lo = wlds_hi + WTAB;
  float *preact = (float *)(smem + (size_t)WTAB * 2 * 2);    // [32][33]

  // gate-indexed weight bases for this layer
  const float *Wh[4] = {p.Whi + (size_t)l * Hv * Hv, p.Whf + (size_t)l * Hv * Hv,
                        p.Who + (size_t)l * Hv * Hv, p.Whc + (size_t)l * Hv * Hv};
  const float *Wx[4];
  if (l == 0) { Wx[0] = p.Wx0i; Wx[1] = p.Wx0f; Wx[2] = p.Wx0o; Wx[3] = p.Wx0c; }
  else {
    size_t o = (size_t)(l - 1) * Hv * Hv;
    Wx[0] = p.Wxi + o; Wx[1] = p.Wxf + o; Wx[2] = p.Wxo + o; Wx[3] = p.Wxc + o;
  }
  const int kx_max = (l == 0) ? Iv : Hv;

  // ---- stage weight slice into LDS in MFMA B-fragment order (hi/lo split) ----
  for (int idx = tid; idx < 2 * NKK * 64; idx += THREADS) {
    int lanei = idx & 63;
    int kk = (idx >> 6) & (NKK - 1);
    int nti = idx >> 11;
    int kbase = kk * 32 + (lanei >> 4) * 8;
    int n = nti * 16 + (lanei & 15); // gate-col within 32: n = jj*4 + g
    int jj = n >> 2, g = n & 3;
    int col = slice * 8 + jj;
    sfrag vh, vl;
#pragma unroll
    for (int j = 0; j < 8; ++j) {
      int k = kbase + j;
      float wv;
      if (k < Hv) wv = Wh[g][(size_t)k * Hv + col];
      else {
        int kx = k - Hv;
        wv = (kx < kx_max) ? Wx[g][(size_t)kx * Hv + col] : 0.f;
      }
      unsigned short h16 = f2bf(wv);
      vh[j] = (short)h16;
      vl[j] = (short)f2bf(wv - bf2f(h16));
    }
    *(sfrag *)&wlds_hi[(size_t)idx * 8] = vh;
    *(sfrag *)&wlds_lo[(size_t)idx * 8] = vl;
  }

  // epilogue thread mapping: bm = batch, um = unit-in-slice
  const int bm = tid >> 3;
  const int um = tid & 7;
  const int jg = slice * 8 + um;
  const float bia_i = p.bi[l * Hv + jg];
  const float bia_f = p.bf[l * Hv + jg];
  const float bia_o = p.bo[l * Hv + jg];
  const float bia_c = p.bc[l * Hv + jg];
  float cstate = 0.f;

  __syncthreads();

  const int m = mt * 16 + (lane & 15); // batch row for A fragment
  const int kgrp = lane >> 4;          // k-group 0..3
  int *flags = p.flags;
  unsigned short *hbuf = p.hbuf;
  const int per_slice = p.per_slice;

  for (int t = 0; t < Tv; ++t) {
    // ---- wait for dependencies (no fences; flags are agent-coherent) ----
    if (per_slice) {
      if (t > 0 && tid < SLICES) {
        const int *fp = &flags[(t * LAYv + l) * SLICES + tid];
        while (__hip_atomic_load(fp, __ATOMIC_RELAXED, __HIP_MEMORY_SCOPE_AGENT) == 0)
          __builtin_amdgcn_s_sleep(1);
      }
      if (l > 0 && tid >= 64 && tid < 64 + SLICES) {
        const int *fp = &flags[((t + 1) * LAYv + (l - 1)) * SLICES + (tid - 64)];
        while (__hip_atomic_load(fp, __ATOMIC_RELAXED, __HIP_MEMORY_SCOPE_AGENT) == 0)
          __builtin_amdgcn_s_sleep(1);
      }
    } else {
      if (tid == 0) {
        if (t > 0) {
          const int *fp = &flags[t * LAYv + l];
          while (__hip_atomic_load(fp, __ATOMIC_RELAXED, __HIP_MEMORY_SCOPE_AGENT) < SLICES)
            __builtin_amdgcn_s_sleep(1);
        }
        if (l > 0) {
          const int *fp = &flags[(t + 1) * LAYv + (l - 1)];
          while (__hip_atomic_load(fp, __ATOMIC_RELAXED, __HIP_MEMORY_SCOPE_AGENT) < SLICES)
            __builtin_amdgcn_s_sleep(1);
        }
      }
    }
    __syncthreads();

    // ---- GEMM [32 x K] * [K x 32] into two independent acc chains ----
    facc acc0 = {0.f, 0.f, 0.f, 0.f};
    facc acc1 = {0.f, 0.f, 0.f, 0.f};
    const unsigned short *hrec =
        hbuf + ((size_t)(t * LAYv + l) * Bv * Hv) + (size_t)m * Hv;
#pragma unroll
    for (int kk = 0; kk < 16; ++kk) { // recurrent half
      int k = kk * 32 + kgrp * 8;
      sfrag a = ld16_agent(hrec + k);
      sfrag bh = *(const sfrag *)&wlds_hi[(size_t)((nt * NKK + kk) * 64 + lane) * 8];
      sfrag bl = *(const sfrag *)&wlds_lo[(size_t)((nt * NKK + kk) * 64 + lane) * 8];
      acc0 = __builtin_amdgcn_mfma_f32_16x16x32_bf16(a, bh, acc0, 0, 0, 0);
      acc1 = __builtin_amdgcn_mfma_f32_16x16x32_bf16(a, bl, acc1, 0, 0, 0);
    }
    if (l == 0) {
#pragma unroll
      for (int kk = 0; kk < 8; ++kk) { // x input half (I=256)
        int kx = kk * 32 + kgrp * 8;
        const float *xp = p.x + ((size_t)m * Tv + t) * Iv + kx;
        f32x4 lo = *(const f32x4 *)xp;
        f32x4 hi = *(const f32x4 *)(xp + 4);
        sfrag a;
#pragma unroll
        for (int j = 0; j < 4; ++j) {
          a[j] = (short)f2bf(lo[j]);
          a[4 + j] = (short)f2bf(hi[j]);
        }
        sfrag bh = *(const sfrag *)&wlds_hi[(size_t)((nt * NKK + 16 + kk) * 64 + lane) * 8];
        sfrag bl = *(const sfrag *)&wlds_lo[(size_t)((nt * NKK + 16 + kk) * 64 + lane) * 8];
        acc0 = __builtin_amdgcn_mfma_f32_16x16x32_bf16(a, bh, acc0, 0, 0, 0);
        acc1 = __builtin_amdgcn_mfma_f32_16x16x32_bf16(a, bl, acc1, 0, 0, 0);
      }
    } else {
      const unsigned short *hin =
          hbuf + ((size_t)((t + 1) * LAYv + (l - 1)) * Bv * Hv) + (size_t)m * Hv;
#pragma unroll
      for (int kk = 0; kk < 16; ++kk) { // input half from layer below
        int k = kk * 32 + kgrp * 8;
        sfrag a = ld16_agent(hin + k);
        sfrag bh = *(const sfrag *)&wlds_hi[(size_t)((nt * NKK + 16 + kk) * 64 + lane) * 8];
        sfrag bl = *(const sfrag *)&wlds_lo[(size_t)((nt * NKK + 16 + kk) * 64 + lane) * 8];
        acc0 = __builtin_amdgcn_mfma_f32_16x16x32_bf16(a, bh, acc0, 0, 0, 0);
        acc1 = __builtin_amdgcn_mfma_f32_16x16x32_bf16(a, bl, acc1, 0, 0, 0);
      }
    }

    // ---- scatter pre-activations to LDS ----
    {
      int row = mt * 16 + kgrp * 4;
      int coln = nt * 16 + (lane & 15);
#pragma unroll
      for (int r = 0; r < 4; ++r)
        preact[(row + r) * 33 + coln] = acc0[r] + acc1[r];
    }
    __syncthreads();

    // ---- gates / state update: one thread per (batch, unit) ----
    float pi = preact[bm * 33 + um * 4 + 0] + bia_i;
    float pf = preact[bm * 33 + um * 4 + 1] + bia_f;
    float po = preact[bm * 33 + um * 4 + 2] + bia_o;
    float pc = preact[bm * 33 + um * 4 + 3] + bia_c;
    float gi = 1.f / (1.f + __expf(-pi));
    float gf = 1.f / (1.f + __expf(-pf));
    float go = 1.f / (1.f + __expf(-po));
    float gc = tanhf(pc);
    cstate = gf * cstate + gi * gc;
    float hval = go * tanhf(cstate);

    // agent-scope store: write-through to coherence point (no fence needed)
    __hip_atomic_store(
        &hbuf[(size_t)((t + 1) * LAYv + l) * Bv * Hv + (size_t)bm * Hv + jg],
        f2bf(hval), __ATOMIC_RELAXED, __HIP_MEMORY_SCOPE_AGENT);
    if (l == LAYv - 1)
      p.out[((size_t)bm * Tv + t) * Hv + jg] = hval;

    asm volatile("s_waitcnt vmcnt(0)" ::: "memory"); // stores ack'd at L3
    __syncthreads(); // all waves past their waitcnt

    if (tid == 0) {
      if (per_slice)
        __hip_atomic_store(&flags[((t + 1) * LAYv + l) * SLICES + slice], 1,
                           __ATOMIC_RELAXED, __HIP_MEMORY_SCOPE_AGENT);
      else
        __hip_atomic_fetch_add(&flags[(t + 1) * LAYv + l], 1,
                               __ATOMIC_RELAXED, __HIP_MEMORY_SCOPE_AGENT);
    }
  }
}

extern "C" void kernel_launch(void *const *d_in, const int *in_sizes, int n_in,
                              void *d_out, int out_size, void *d_ws, size_t ws_size,
                              hipStream_t stream) {
  Params prm;
  prm.x = (const float *)d_in[0];
  prm.Wx0i = (const float *)d_in[1];
  prm.Wx0f = (const float *)d_in[2];
  prm.Wx0o = (const float *)d_in[3];
  prm.Wx0c = (const float *)d_in[4];
  prm.Wxi = (const float *)d_in[5];
  prm.Wxf = (const float *)d_in[6];
  prm.Wxo = (const float *)d_in[7];
  prm.Wxc = (const float *)d_in[8];
  prm.Whi = (const float *)d_in[9];
  prm.Whf = (const float *)d_in[10];
  prm.Who = (const float *)d_in[11];
  prm.Whc = (const float *)d_in[12];
  prm.bi = (const float *)d_in[13];
  prm.bf = (const float *)d_in[14];
  prm.bo = (const float *)d_in[15];
  prm.bc = (const float *)d_in[16];
  prm.out = (float *)d_out;

  size_t hbytes = (size_t)(Tv + 1) * LAYv * Bv * Hv * sizeof(unsigned short);
  size_t f_small = (size_t)(Tv + 1) * LAYv * sizeof(int);
  size_t f_big = (size_t)(Tv + 1) * LAYv * SLICES * sizeof(int);
  if (ws_size < hbytes + f_small) return;
  prm.hbuf = (unsigned short *)d_ws;
  prm.flags = (int *)((char *)d_ws + hbytes);
  prm.per_slice = (ws_size >= hbytes + f_big) ? 1 : 0;
  size_t fbytes = prm.per_slice ? f_big : f_small;

  // reset flags and the t=0 zero h-slot every call (deterministic replays)
  hipMemsetAsync(prm.flags, 0, fbytes, stream);
  hipMemsetAsync(d_ws, 0, (size_t)LAYv * Bv * Hv * sizeof(unsigned short), stream);

  hipFuncSetAttribute(reinterpret_cast<const void *>(lstm_pipeline),
                      hipFuncAttributeMaxDynamicSharedMemorySize, (int)SMEM_BYTES);

  void *args[] = {(void *)&prm};
  hipLaunchCooperativeKernel(reinterpret_cast<void *>(lstm_pipeline),
                             dim3(LAYv * SLICES), dim3(THREADS), args,
                             SMEM_BYTES, stream);
}